// Round 11
// baseline (108.083 us; speedup 1.0000x reference)
//
#include <hip/hip_runtime.h>

// Weighted Chamfer, B=4, N=M=8192, D=3, fp32 in/out.
// out = (1/B)*[ sum_b sum_n w*min_m d2 + sum_b sum_m min_n d2 ]
//
// One v_mfma_f32_32x32x16_bf16 yields a 32x32 tile of d2 = s2 + t2 - 2 s.t
// via K-slot packing with split-bf16 compensation (verified r2-r10):
//   k0-8: {hs,hs,ls}x * {-2ht,-2lt,-2ht}x per dim; k9-10: {h,l}(s2)*1;
//   k11-12: 1*{h,l}(t2); k13-15: zero.  Error ~1e-5 (threshold 5.76).
// C/D layout (m74/m101): col=lane&31, row=(reg&3)+8*(reg>>2)+4*(lane>>5).
//
// Round 11: DIAGNOSTIC REP=3 on the best kernel (r8, 83.9 us, scan ~25 us).
// r10 falsified the AGPR-tax theory (shrinking D to 4 regs REGRESSED), so
// the 5x gap between scan's ~5 us issue floor and ~25 us measured is still
// unexplained - and scan has been invisible in rocprof top-5 since r4
// (every variant < the five ~42 us ws-re-poison fills; r9's REP=2 missed by
// ~4 us). REP=3: three block-sets do byte-identical work and identical
// writes (race-safe) -> scan ~48 us surfaces WITH counters. Body identical
// to r8 so the counters describe the keeper. Total ~105-110 us this round.

typedef short bf16x8 __attribute__((ext_vector_type(8)));
typedef float f32x16 __attribute__((ext_vector_type(16)));

#define BB 4
#define NP 8192
#define NFRAG (NP / 32)          // 256 32-point fragments per batch
#define RF 4                     // query-frags per wave (128 queries)
#define WAVES 4                  // 256 threads; 512 queries per block
#define QBLOCKS 16               // 8192 / 512
#define CFRAGS 32                // DB frags per LDS stage (1024 pts, 32 KB)
#define NCHG 8                   // DB chunks (8192 / 1024)
#define REP 3                    // diagnostic work multiplier

__device__ __forceinline__ unsigned short bf16r(float x) {
    unsigned u = __float_as_uint(x);
    unsigned r = u + 0x7FFFu + ((u >> 16) & 1u);
    return (unsigned short)(r >> 16);
}
__device__ __forceinline__ float bf16f(unsigned short h) {
    return __uint_as_float(((unsigned)h) << 16);
}

// ---- prep: A-pack and B-pack (32x32x16 fragment layout) for both clouds ----
__global__ __launch_bounds__(256) void prep_kernel(
    const float* __restrict__ src, const float* __restrict__ tgt,
    uint4* __restrict__ aS, uint4* __restrict__ bS,
    uint4* __restrict__ aT, uint4* __restrict__ bT,
    float* __restrict__ out)
{
    int gid = blockIdx.x * 256 + threadIdx.x;   // 2*4*256*64 = 131072
    if (gid == 0) out[0] = 0.0f;
    int cloud = gid >> 16;
    int rem   = gid & 65535;
    int b     = rem >> 14;
    int f     = (rem >> 6) & (NFRAG - 1);
    int lane  = rem & 63;
    int half  = lane >> 5;
    int p     = f * 32 + (lane & 31);

    const float* c = cloud ? tgt : src;
    size_t base = ((size_t)b * NP + p) * 3;
    float x = c[base + 0], y = c[base + 1], z = c[base + 2];
    float n2 = x * x + y * y + z * z;

    unsigned short hx = bf16r(x), lx = bf16r(x - bf16f(hx));
    unsigned short hy = bf16r(y), ly = bf16r(y - bf16f(hy));
    unsigned short hz = bf16r(z), lz = bf16r(z - bf16f(hz));
    unsigned short h2 = bf16r(n2), l2 = bf16r(n2 - bf16f(h2));
    unsigned short nhx = bf16r(-2.f * bf16f(hx)), nlx = bf16r(-2.f * bf16f(lx));
    unsigned short nhy = bf16r(-2.f * bf16f(hy)), nly = bf16r(-2.f * bf16f(ly));
    unsigned short nhz = bf16r(-2.f * bf16f(hz)), nlz = bf16r(-2.f * bf16f(lz));
    const unsigned ONE = 0x3F80u;

    uint4 pa, pb;
    if (half == 0) {   // k = 0..7
        pa.x = (unsigned)hx | ((unsigned)hx << 16);
        pa.y = (unsigned)lx | ((unsigned)hy << 16);
        pa.z = (unsigned)hy | ((unsigned)ly << 16);
        pa.w = (unsigned)hz | ((unsigned)hz << 16);
        pb.x = (unsigned)nhx | ((unsigned)nlx << 16);
        pb.y = (unsigned)nhx | ((unsigned)nhy << 16);
        pb.z = (unsigned)nly | ((unsigned)nhy << 16);
        pb.w = (unsigned)nhz | ((unsigned)nlz << 16);
    } else {           // k = 8..15 (13..15 zero)
        pa.x = (unsigned)lz | ((unsigned)h2 << 16);
        pa.y = (unsigned)l2 | (ONE << 16);
        pa.z = ONE;
        pa.w = 0u;
        pb.x = (unsigned)nhz | (ONE << 16);
        pb.y = ONE | ((unsigned)h2 << 16);
        pb.z = (unsigned)l2;
        pb.w = 0u;
    }
    size_t off = ((size_t)b * NFRAG + f) * 64 + lane;
    (cloud ? aT : aS)[off] = pa;
    (cloud ? bT : bS)[off] = pb;
}

// ---- scan: DB rows from LDS, queries in regs, per-lane scalar running min ----
__global__ __launch_bounds__(256, 4) void scan_kernel(
    const uint4* __restrict__ aS, const uint4* __restrict__ bS,
    const uint4* __restrict__ aT, const uint4* __restrict__ bT,
    float* __restrict__ part)   // part[dir][b][ch][query]
{
    __shared__ uint4 ash[CFRAGS * 64];          // 32 KB DB stage
    const int tid = threadIdx.x;
    const int lane = tid & 63, wave = tid >> 6;
    const int qb = blockIdx.x, b = blockIdx.y;
    int z = blockIdx.z;
    if (z >= 16) z -= 16;                       // rep fold (identical work)
    if (z >= 16) z -= 16;
    const int ch = z & (NCHG - 1);
    const int dir = z >> 3;

    // dir 0: queries = source (B-op bS), DB = target (A-op aT); dir 1 mirrored.
    const uint4* qfr = dir ? bT : bS;
    const uint4* dfr = dir ? aS : aT;

    // stage DB chunk (32 frags, 8 uint4/thread, coalesced)
    const uint4* dsrc = dfr + ((size_t)b * NFRAG + ch * CFRAGS) * 64;
#pragma unroll
    for (int j = 0; j < 8; j++) ash[tid + j * 256] = dsrc[tid + j * 256];

    // this wave's query fragments (B operand, registers all sweep)
    const uint4* qsrc = qfr + ((size_t)b * NFRAG + qb * (WAVES * RF) + wave * RF) * 64 + lane;
    bf16x8 qfrag[RF];
#pragma unroll
    for (int rf = 0; rf < RF; rf++) {
        uint4 t = qsrc[rf * 64];
        qfrag[rf] = *(bf16x8*)&t;
    }

    float vminq[RF];
#pragma unroll
    for (int rf = 0; rf < RF; rf++) vminq[rf] = 1e30f;
    f32x16 zero = {};
    __syncthreads();                            // the block's only barrier

    for (int t = 0; t < CFRAGS; t += 2) {
        bf16x8 a0 = *(bf16x8*)&ash[t * 64 + lane];
        bf16x8 a1 = *(bf16x8*)&ash[(t + 1) * 64 + lane];
#pragma unroll
        for (int rf = 0; rf < RF; rf++) {
            f32x16 dA = __builtin_amdgcn_mfma_f32_32x32x16_bf16(a0, qfrag[rf], zero, 0, 0, 0);
            f32x16 dB = __builtin_amdgcn_mfma_f32_32x32x16_bf16(a1, qfrag[rf], zero, 0, 0, 0);
#pragma unroll
            for (int i = 0; i < 16; i++)
                vminq[rf] = fminf(fminf(dA[i], dB[i]), vminq[rf]);  // v_min3_f32
        }
    }

    // finalize: lane^32 holds the other 16 DB rows of the same query column
    float* pbase = part + ((size_t)(dir * BB + b) * NCHG + ch) * NP
                 + qb * (WAVES * RF * 32) + wave * (RF * 32);
#pragma unroll
    for (int rf = 0; rf < RF; rf++) {
        float v = fminf(vminq[rf], __shfl_xor(vminq[rf], 32, 64));
        if (lane < 32) pbase[rf * 32 + lane] = v;
    }
}

// ---- reduce: min over DB chunks, weight, sum, atomicAdd ----
__global__ __launch_bounds__(256) void reduce_kernel(
    const float* __restrict__ weights, const float* __restrict__ part,
    float* __restrict__ out)
{
    int tid = threadIdx.x;
    int gid = blockIdx.x * 256 + tid;       // 0 .. 65535
    int dir = gid >> 15;
    int r   = gid & 32767;
    int b   = r >> 13;
    int q   = r & (NP - 1);

    const float* p = part + ((size_t)(dir * BB + b) * NCHG) * NP + q;
    float mn = 1e30f;
#pragma unroll
    for (int i = 0; i < NCHG; i++) mn = fminf(mn, p[(size_t)i * NP]);
    float w = dir ? 1.0f : weights[b * NP + q];
    float v = mn * w * (1.0f / BB);
#pragma unroll
    for (int off = 32; off; off >>= 1) v += __shfl_down(v, off, 64);
    __shared__ float ls[4];
    if ((tid & 63) == 0) ls[tid >> 6] = v;
    __syncthreads();
    if (tid == 0) atomicAdd(out, ls[0] + ls[1] + ls[2] + ls[3]);
}

extern "C" void kernel_launch(void* const* d_in, const int* in_sizes, int n_in,
                              void* d_out, int out_size, void* d_ws, size_t ws_size,
                              hipStream_t stream) {
    const float* src = (const float*)d_in[0];   // (B, N, 3)
    const float* tgt = (const float*)d_in[1];   // (B, M, 3)
    const float* wgt = (const float*)d_in[2];   // (B, N)
    float* out = (float*)d_out;

    char* ws = (char*)d_ws;
    const size_t FRAG_BYTES = (size_t)BB * NFRAG * 64 * 16;   // 1 MB each
    uint4* aS = (uint4*)(ws + 0 * FRAG_BYTES);
    uint4* bS = (uint4*)(ws + 1 * FRAG_BYTES);
    uint4* aT = (uint4*)(ws + 2 * FRAG_BYTES);
    uint4* bT = (uint4*)(ws + 3 * FRAG_BYTES);
    float* part = (float*)(ws + 4 * FRAG_BYTES);              // 2 MB

    prep_kernel<<<dim3(512), dim3(256), 0, stream>>>(src, tgt, aS, bS, aT, bT, out);
    scan_kernel<<<dim3(QBLOCKS, BB, 2 * NCHG * REP), dim3(256), 0, stream>>>(aS, bS, aT, bT, part);
    reduce_kernel<<<dim3(256), dim3(256), 0, stream>>>(wgt, part, out);
}

// Round 13
// 81.572 us; speedup vs baseline: 1.3250x; 1.3250x over previous
//
#include <hip/hip_runtime.h>

// Weighted Chamfer, B=4, N=M=8192, D=3, fp32 in/out.
// out = (1/B)*[ sum_b sum_n w*min_m d2 + sum_b sum_m min_n d2 ]
//
// One v_mfma_f32_32x32x16_bf16 yields a 32x32 tile of d2 = s2 + t2 - 2 s.t
// via K-slot packing with split-bf16 compensation (verified r2-r11):
//   k0-8: {hs,hs,ls}x * {-2ht,-2lt,-2ht}x per dim; k9-10: {h,l}(s2)*1;
//   k11-12: 1*{h,l}(t2); k13-15: zero.  Error ~1e-5 (threshold 5.76).
// C/D layout (m74/m101): col=lane&31, row=(reg&3)+8*(reg>>2)+4*(lane>>5).
//
// Round 13: r12's inline-asm v_min3_f32 broke correctness (absmax 6304;
// cause unresolved - do NOT feed MFMA results through inline asm). Same
// fusion goal achieved safely: accumulate the running min in INTEGER domain.
// d2 >= -1e-5, and for positive-or-negligibly-negative floats the IEEE bit
// pattern is order-isomorphic to signed i32 (negatives only occur within
// ~1e-5 of 0, where any mis-selection errs by <=3e-5 << 5.76 threshold).
// min(min(a,b),c) on i32 folds to v_min3_i32 unconditionally (no NaN-
// semantics blocker, unlike fminf) -> 0.5 VALU inst per d2 value.
// r11 counters priced the pipes: MFMA 6.9 us + VALU(unfused) 6.8 us per
// work-unit, fixed ~13 us; fusing halves the VALU term.

typedef short bf16x8 __attribute__((ext_vector_type(8)));
typedef float f32x16 __attribute__((ext_vector_type(16)));

#define BB 4
#define NP 8192
#define NFRAG (NP / 32)          // 256 32-point fragments per batch
#define RF 4                     // query-frags per wave (128 queries)
#define WAVES 4                  // 256 threads; 512 queries per block
#define QBLOCKS 16               // 8192 / 512
#define CFRAGS 32                // DB frags per LDS stage (1024 pts, 32 KB)
#define NCHG 8                   // DB chunks (8192 / 1024)

__device__ __forceinline__ int smin3(int a, int b, int c) {
    int m = a < b ? a : b;
    return (m < c) ? m : c;      // folds to v_min3_i32
}

__device__ __forceinline__ unsigned short bf16r(float x) {
    unsigned u = __float_as_uint(x);
    unsigned r = u + 0x7FFFu + ((u >> 16) & 1u);
    return (unsigned short)(r >> 16);
}
__device__ __forceinline__ float bf16f(unsigned short h) {
    return __uint_as_float(((unsigned)h) << 16);
}

// ---- prep: A-pack and B-pack (32x32x16 fragment layout) for both clouds ----
__global__ __launch_bounds__(256) void prep_kernel(
    const float* __restrict__ src, const float* __restrict__ tgt,
    uint4* __restrict__ aS, uint4* __restrict__ bS,
    uint4* __restrict__ aT, uint4* __restrict__ bT,
    float* __restrict__ out)
{
    int gid = blockIdx.x * 256 + threadIdx.x;   // 2*4*256*64 = 131072
    if (gid == 0) out[0] = 0.0f;
    int cloud = gid >> 16;
    int rem   = gid & 65535;
    int b     = rem >> 14;
    int f     = (rem >> 6) & (NFRAG - 1);
    int lane  = rem & 63;
    int half  = lane >> 5;
    int p     = f * 32 + (lane & 31);

    const float* c = cloud ? tgt : src;
    size_t base = ((size_t)b * NP + p) * 3;
    float x = c[base + 0], y = c[base + 1], z = c[base + 2];
    float n2 = x * x + y * y + z * z;

    unsigned short hx = bf16r(x), lx = bf16r(x - bf16f(hx));
    unsigned short hy = bf16r(y), ly = bf16r(y - bf16f(hy));
    unsigned short hz = bf16r(z), lz = bf16r(z - bf16f(hz));
    unsigned short h2 = bf16r(n2), l2 = bf16r(n2 - bf16f(h2));
    unsigned short nhx = bf16r(-2.f * bf16f(hx)), nlx = bf16r(-2.f * bf16f(lx));
    unsigned short nhy = bf16r(-2.f * bf16f(hy)), nly = bf16r(-2.f * bf16f(ly));
    unsigned short nhz = bf16r(-2.f * bf16f(hz)), nlz = bf16r(-2.f * bf16f(lz));
    const unsigned ONE = 0x3F80u;

    uint4 pa, pb;
    if (half == 0) {   // k = 0..7
        pa.x = (unsigned)hx | ((unsigned)hx << 16);
        pa.y = (unsigned)lx | ((unsigned)hy << 16);
        pa.z = (unsigned)hy | ((unsigned)ly << 16);
        pa.w = (unsigned)hz | ((unsigned)hz << 16);
        pb.x = (unsigned)nhx | ((unsigned)nlx << 16);
        pb.y = (unsigned)nhx | ((unsigned)nhy << 16);
        pb.z = (unsigned)nly | ((unsigned)nhy << 16);
        pb.w = (unsigned)nhz | ((unsigned)nlz << 16);
    } else {           // k = 8..15 (13..15 zero)
        pa.x = (unsigned)lz | ((unsigned)h2 << 16);
        pa.y = (unsigned)l2 | (ONE << 16);
        pa.z = ONE;
        pa.w = 0u;
        pb.x = (unsigned)nhz | (ONE << 16);
        pb.y = ONE | ((unsigned)h2 << 16);
        pb.z = (unsigned)l2;
        pb.w = 0u;
    }
    size_t off = ((size_t)b * NFRAG + f) * 64 + lane;
    (cloud ? aT : aS)[off] = pa;
    (cloud ? bT : bS)[off] = pb;
}

// ---- scan: DB rows from LDS, queries in regs, per-lane integer running min ----
__global__ __launch_bounds__(256, 4) void scan_kernel(
    const uint4* __restrict__ aS, const uint4* __restrict__ bS,
    const uint4* __restrict__ aT, const uint4* __restrict__ bT,
    float* __restrict__ part)   // part[dir][b][ch][query]
{
    __shared__ uint4 ash[CFRAGS * 64];          // 32 KB DB stage
    const int tid = threadIdx.x;
    const int lane = tid & 63, wave = tid >> 6;
    const int qb = blockIdx.x, b = blockIdx.y;
    const int dir = blockIdx.z >> 3, ch = blockIdx.z & (NCHG - 1);

    // dir 0: queries = source (B-op bS), DB = target (A-op aT); dir 1 mirrored.
    const uint4* qfr = dir ? bT : bS;
    const uint4* dfr = dir ? aS : aT;

    // stage DB chunk (32 frags, 8 uint4/thread, coalesced)
    const uint4* dsrc = dfr + ((size_t)b * NFRAG + ch * CFRAGS) * 64;
#pragma unroll
    for (int j = 0; j < 8; j++) ash[tid + j * 256] = dsrc[tid + j * 256];

    // this wave's query fragments (B operand, registers all sweep)
    const uint4* qsrc = qfr + ((size_t)b * NFRAG + qb * (WAVES * RF) + wave * RF) * 64 + lane;
    bf16x8 qfrag[RF];
#pragma unroll
    for (int rf = 0; rf < RF; rf++) {
        uint4 t = qsrc[rf * 64];
        qfrag[rf] = *(bf16x8*)&t;
    }

    int vmini[RF];
#pragma unroll
    for (int rf = 0; rf < RF; rf++) vmini[rf] = __float_as_int(1e30f);
    f32x16 zero = {};
    __syncthreads();                            // the block's only barrier

    for (int t = 0; t < CFRAGS; t += 2) {
        bf16x8 a0 = *(bf16x8*)&ash[t * 64 + lane];
        bf16x8 a1 = *(bf16x8*)&ash[(t + 1) * 64 + lane];
#pragma unroll
        for (int rf = 0; rf < RF; rf++) {
            f32x16 dA = __builtin_amdgcn_mfma_f32_32x32x16_bf16(a0, qfrag[rf], zero, 0, 0, 0);
            f32x16 dB = __builtin_amdgcn_mfma_f32_32x32x16_bf16(a1, qfrag[rf], zero, 0, 0, 0);
#pragma unroll
            for (int i = 0; i < 16; i++)
                vmini[rf] = smin3(__float_as_int(dA[i]), __float_as_int(dB[i]),
                                  vmini[rf]);           // v_min3_i32
        }
    }

    // finalize: lane^32 holds the other 16 DB rows of the same query column
    float* pbase = part + ((size_t)(dir * BB + b) * NCHG + ch) * NP
                 + qb * (WAVES * RF * 32) + wave * (RF * 32);
#pragma unroll
    for (int rf = 0; rf < RF; rf++) {
        float v = __int_as_float(vmini[rf]);
        v = fminf(v, __shfl_xor(v, 32, 64));
        if (lane < 32) pbase[rf * 32 + lane] = v;
    }
}

// ---- reduce: min over DB chunks, weight, sum, atomicAdd ----
__global__ __launch_bounds__(256) void reduce_kernel(
    const float* __restrict__ weights, const float* __restrict__ part,
    float* __restrict__ out)
{
    int tid = threadIdx.x;
    int gid = blockIdx.x * 256 + tid;       // 0 .. 65535
    int dir = gid >> 15;
    int r   = gid & 32767;
    int b   = r >> 13;
    int q   = r & (NP - 1);

    const float* p = part + ((size_t)(dir * BB + b) * NCHG) * NP + q;
    float mn = 1e30f;
#pragma unroll
    for (int i = 0; i < NCHG; i++) mn = fminf(mn, p[(size_t)i * NP]);
    float w = dir ? 1.0f : weights[b * NP + q];
    float v = mn * w * (1.0f / BB);
#pragma unroll
    for (int off = 32; off; off >>= 1) v += __shfl_down(v, off, 64);
    __shared__ float ls[4];
    if ((tid & 63) == 0) ls[tid >> 6] = v;
    __syncthreads();
    if (tid == 0) atomicAdd(out, ls[0] + ls[1] + ls[2] + ls[3]);
}

extern "C" void kernel_launch(void* const* d_in, const int* in_sizes, int n_in,
                              void* d_out, int out_size, void* d_ws, size_t ws_size,
                              hipStream_t stream) {
    const float* src = (const float*)d_in[0];   // (B, N, 3)
    const float* tgt = (const float*)d_in[1];   // (B, M, 3)
    const float* wgt = (const float*)d_in[2];   // (B, N)
    float* out = (float*)d_out;

    char* ws = (char*)d_ws;
    const size_t FRAG_BYTES = (size_t)BB * NFRAG * 64 * 16;   // 1 MB each
    uint4* aS = (uint4*)(ws + 0 * FRAG_BYTES);
    uint4* bS = (uint4*)(ws + 1 * FRAG_BYTES);
    uint4* aT = (uint4*)(ws + 2 * FRAG_BYTES);
    uint4* bT = (uint4*)(ws + 3 * FRAG_BYTES);
    float* part = (float*)(ws + 4 * FRAG_BYTES);              // 2 MB

    prep_kernel<<<dim3(512), dim3(256), 0, stream>>>(src, tgt, aS, bS, aT, bT, out);
    scan_kernel<<<dim3(QBLOCKS, BB, 2 * NCHG), dim3(256), 0, stream>>>(aS, bS, aT, bT, part);
    reduce_kernel<<<dim3(256), dim3(256), 0, stream>>>(wgt, part, out);
}

// Round 14
// 76.919 us; speedup vs baseline: 1.4052x; 1.0605x over previous
//
#include <hip/hip_runtime.h>

// Weighted Chamfer, B=4, N=M=8192, D=3, fp32 in/out.
// out = (1/B)*[ sum_b sum_n w*min_m d2 + sum_b sum_m min_n d2 ]
//
// One v_mfma_f32_32x32x16_bf16 yields a 32x32 tile of d2 = s2 + t2 - 2 s.t
// via K-slot packing with split-bf16 compensation (verified r2-r13):
//   A(plain)  half0 {hx,hx,lx,hy,hy,ly,hz,hz} half1 {lz,h2,l2,1,1,0,0,0}
//   B(-2 scl) half0 {nhx,nlx,nhx,nhy,nly,nhy,nhz,nlz} half1 {nhz,1,1,h2,l2,0,0,0}
//   Error ~1e-5 (threshold 5.76). C/D layout: col=lane&31.
// Transposed operands (r8): DB = A staged in LDS, queries = B in registers ->
// per-lane scalar running min per query. Min accumulated in i32 domain
// (r13): d2 >= -1e-5 so IEEE bits are order-isomorphic; min-chain folds to
// v_min3_i32 (fminf blocks the fold on NaN semantics; inline asm broke, r12).
//
// Round 14: SELF-PACKING scan - prep kernel deleted. Each block packs its
// 1024-pt DB chunk raw->LDS (12 KB read vs 32 KB frag read) and each lane
// packs its query B-frags in registers (-2*bf16 done in int bits:
// (h^0x8000)+0x80, exact). Removes prep dispatch + stream gap + 8 MB ws
// frag traffic. Pipeline: scan -> reduce. out zeroed by scan block (0,0,0)
// (stream order guarantees it precedes reduce's atomics).

typedef short bf16x8 __attribute__((ext_vector_type(8)));
typedef float f32x16 __attribute__((ext_vector_type(16)));

#define BB 4
#define NP 8192
#define RF 4                     // query-frags per wave (128 queries)
#define WAVES 4                  // 256 threads; 512 queries per block
#define QBLOCKS 16               // 8192 / 512
#define CFRAGS 32                // DB frags per LDS stage (1024 pts, 32 KB)
#define NCHG 8                   // DB chunks (8192 / 1024)

__device__ __forceinline__ int smin3(int a, int b, int c) {
    int m = a < b ? a : b;
    return (m < c) ? m : c;      // folds to v_min3_i32
}
__device__ __forceinline__ unsigned short bf16r(float x) {
    unsigned u = __float_as_uint(x);
    unsigned r = u + 0x7FFFu + ((u >> 16) & 1u);
    return (unsigned short)(r >> 16);
}
__device__ __forceinline__ float bf16f(unsigned short h) {
    return __uint_as_float(((unsigned)h) << 16);
}
// -2 * bf16(h), exact in bits (sign flip + exponent+1); h==+-0 -> tiny
// denormal ~1e-38 whose products are << 1e-5 packing error. [verified slot math]
__device__ __forceinline__ unsigned short neg2(unsigned short h) {
    return (unsigned short)((h ^ 0x8000u) + 0x0080u);
}

struct Pack {
    unsigned short hx, lx, hy, ly, hz, lz, h2, l2;
};
__device__ __forceinline__ Pack mkpack(float x, float y, float z) {
    Pack p;
    p.hx = bf16r(x); p.lx = bf16r(x - bf16f(p.hx));
    p.hy = bf16r(y); p.ly = bf16r(y - bf16f(p.hy));
    p.hz = bf16r(z); p.lz = bf16r(z - bf16f(p.hz));
    float n2 = x * x + y * y + z * z;
    p.h2 = bf16r(n2); p.l2 = bf16r(n2 - bf16f(p.h2));
    return p;
}

#define ONE 0x3F80u

// ---- scan: self-packing; DB rows from LDS, queries in regs, i32 min3 ----
__global__ __launch_bounds__(256, 4) void scan_kernel(
    const float* __restrict__ src, const float* __restrict__ tgt,
    float* __restrict__ part,   // part[dir][b][ch][query]
    float* __restrict__ out)
{
    __shared__ uint4 ash[CFRAGS * 64];          // 32 KB DB stage (A-packs)
    const int tid = threadIdx.x;
    const int lane = tid & 63, wave = tid >> 6;
    const int qb = blockIdx.x, b = blockIdx.y;
    const int dir = blockIdx.z >> 3, ch = blockIdx.z & (NCHG - 1);

    if (blockIdx.x == 0 && blockIdx.y == 0 && blockIdx.z == 0 && tid == 0)
        out[0] = 0.0f;

    // dir 0: queries = source, DB = target; dir 1 mirrored.
    const float* dbc = (dir ? src : tgt) + ((size_t)b * NP + ch * 1024) * 3;
    const float* qc  = (dir ? tgt : src) + ((size_t)b * NP + qb * (WAVES * RF * 32)) * 3;

    // ---- stage DB chunk: 4 points/thread, pack A-layout into LDS ----
#pragma unroll
    for (int j = 0; j < 4; j++) {
        int i = tid + j * 256;
        float x = dbc[i * 3 + 0], y = dbc[i * 3 + 1], z = dbc[i * 3 + 2];
        Pack p = mkpack(x, y, z);
        uint4 h0, h1;
        h0.x = (unsigned)p.hx | ((unsigned)p.hx << 16);
        h0.y = (unsigned)p.lx | ((unsigned)p.hy << 16);
        h0.z = (unsigned)p.hy | ((unsigned)p.ly << 16);
        h0.w = (unsigned)p.hz | ((unsigned)p.hz << 16);
        h1.x = (unsigned)p.lz | ((unsigned)p.h2 << 16);
        h1.y = (unsigned)p.l2 | (ONE << 16);
        h1.z = ONE;
        h1.w = 0u;
        int f = i >> 5, m = i & 31;
        ash[f * 64 + m]      = h0;
        ash[f * 64 + 32 + m] = h1;
    }

    // ---- pack this lane's query B-frags in registers ----
    const int half = lane >> 5, m = lane & 31;
    bf16x8 qfrag[RF];
#pragma unroll
    for (int rf = 0; rf < RF; rf++) {
        int q = wave * (RF * 32) + rf * 32 + m;
        float x = qc[q * 3 + 0], y = qc[q * 3 + 1], z = qc[q * 3 + 2];
        Pack p = mkpack(x, y, z);
        unsigned short nhx = neg2(p.hx), nlx = neg2(p.lx);
        unsigned short nhy = neg2(p.hy), nly = neg2(p.ly);
        unsigned short nhz = neg2(p.hz), nlz = neg2(p.lz);
        uint4 v;
        if (half == 0) {
            v.x = (unsigned)nhx | ((unsigned)nlx << 16);
            v.y = (unsigned)nhx | ((unsigned)nhy << 16);
            v.z = (unsigned)nly | ((unsigned)nhy << 16);
            v.w = (unsigned)nhz | ((unsigned)nlz << 16);
        } else {
            v.x = (unsigned)nhz | (ONE << 16);
            v.y = ONE | ((unsigned)p.h2 << 16);
            v.z = (unsigned)p.l2;
            v.w = 0u;
        }
        qfrag[rf] = *(bf16x8*)&v;
    }

    int vmini[RF];
#pragma unroll
    for (int rf = 0; rf < RF; rf++) vmini[rf] = __float_as_int(1e30f);
    f32x16 zero = {};
    __syncthreads();                            // the block's only barrier

    for (int t = 0; t < CFRAGS; t += 2) {
        bf16x8 a0 = *(bf16x8*)&ash[t * 64 + lane];
        bf16x8 a1 = *(bf16x8*)&ash[(t + 1) * 64 + lane];
#pragma unroll
        for (int rf = 0; rf < RF; rf++) {
            f32x16 dA = __builtin_amdgcn_mfma_f32_32x32x16_bf16(a0, qfrag[rf], zero, 0, 0, 0);
            f32x16 dB = __builtin_amdgcn_mfma_f32_32x32x16_bf16(a1, qfrag[rf], zero, 0, 0, 0);
#pragma unroll
            for (int i = 0; i < 16; i++)
                vmini[rf] = smin3(__float_as_int(dA[i]), __float_as_int(dB[i]),
                                  vmini[rf]);           // v_min3_i32
        }
    }

    // finalize: lane^32 holds the other 16 DB rows of the same query column
    float* pbase = part + ((size_t)(dir * BB + b) * NCHG + ch) * NP
                 + qb * (WAVES * RF * 32) + wave * (RF * 32);
#pragma unroll
    for (int rf = 0; rf < RF; rf++) {
        float v = __int_as_float(vmini[rf]);
        v = fminf(v, __shfl_xor(v, 32, 64));
        if (lane < 32) pbase[rf * 32 + lane] = v;
    }
}

// ---- reduce: min over DB chunks, weight, sum, atomicAdd ----
__global__ __launch_bounds__(256) void reduce_kernel(
    const float* __restrict__ weights, const float* __restrict__ part,
    float* __restrict__ out)
{
    int tid = threadIdx.x;
    int gid = blockIdx.x * 256 + tid;       // 0 .. 65535
    int dir = gid >> 15;
    int r   = gid & 32767;
    int b   = r >> 13;
    int q   = r & (NP - 1);

    const float* p = part + ((size_t)(dir * BB + b) * NCHG) * NP + q;
    float mn = 1e30f;
#pragma unroll
    for (int i = 0; i < NCHG; i++) mn = fminf(mn, p[(size_t)i * NP]);
    float w = dir ? 1.0f : weights[b * NP + q];
    float v = mn * w * (1.0f / BB);
#pragma unroll
    for (int off = 32; off; off >>= 1) v += __shfl_down(v, off, 64);
    __shared__ float ls[4];
    if ((tid & 63) == 0) ls[tid >> 6] = v;
    __syncthreads();
    if (tid == 0) atomicAdd(out, ls[0] + ls[1] + ls[2] + ls[3]);
}

extern "C" void kernel_launch(void* const* d_in, const int* in_sizes, int n_in,
                              void* d_out, int out_size, void* d_ws, size_t ws_size,
                              hipStream_t stream) {
    const float* src = (const float*)d_in[0];   // (B, N, 3)
    const float* tgt = (const float*)d_in[1];   // (B, M, 3)
    const float* wgt = (const float*)d_in[2];   // (B, N)
    float* out = (float*)d_out;

    float* part = (float*)d_ws;                 // 2 MB: [2][BB][NCHG][NP]

    scan_kernel<<<dim3(QBLOCKS, BB, 2 * NCHG), dim3(256), 0, stream>>>(
        src, tgt, part, out);
    reduce_kernel<<<dim3(256), dim3(256), 0, stream>>>(wgt, part, out);
}